// Round 9
// baseline (3005.803 us; speedup 1.0000x reference)
//
#include <hip/hip_runtime.h>
#include <stdint.h>

// LWTA MLP, decision/value-split.
//   k1a: dense fp32 GEMM -> winner idx + fp32 winner value + uncertainty flags
//   k1c: fp64 exact resolve of flagged L1 blocks (idx + value)
//   k2a: sparse fp32 GEMM v5 (8 rows/wave, low-VGPR, conflict-free gather)
//   k2b: fp64 resolve of flagged L2 blocks, recomputing h1 fp64 on the fly
//   k3 : sparse fp32 GEMM v5 -> dense out
// fp32 h1 values suffice for the L2 bulk: value err ~1e-6 -> L2 pre-act
// perturbation ~2.4e-7 << EPS2=1e-4 flag threshold; flagged blocks get a
// full fp64 recompute (x.W1 dots) in k2b. k1b (fp64 winner pass) deleted.
// v5: ROWS=8/wave so acc=32 VGPRs -> total ~60 VGPR -> 8 waves/SIMD
// (v4 at 80 VGPR capped at 6; occupancy was 24% and gather latency-bound).
// Metadata TRANSPOSED [kblock][8192]. No __launch_bounds__ min-waves.

#define EPS1 3.0e-4f
#define EPS2 1.0e-4f
#define MST  8192L   // metadata row stride (batch size)
#define SB   260     // sparse-GEMM LDS row stride (words)

// ---------------------------------------------------------------------------
// k1a: dense fp32 GEMM, 128x256 tile, BK=32, LDS-staged (proven form).
#define BSTR1 260

__global__ __launch_bounds__(256)
void k1a_dense_f32_flags(const float* __restrict__ A, const float* __restrict__ Bw,
                         const float* __restrict__ bias, int K,
                         float* __restrict__ vOut,
                         uint8_t* __restrict__ iOut, uint8_t* __restrict__ fOut)
{
    __shared__ float As[32 * 132];
    __shared__ float Bs[32 * BSTR1];
    const int t = threadIdx.x, tx = t & 15, ty = t >> 4;
    const long m0 = (long)blockIdx.y * 128, n0 = (long)blockIdx.x * 256;

    float acc[8][4][4];
#pragma unroll
    for (int r = 0; r < 8; ++r)
#pragma unroll
        for (int g = 0; g < 4; ++g)
#pragma unroll
            for (int d = 0; d < 4; ++d) acc[r][g][d] = 0.f;

    for (int k0 = 0; k0 < K; k0 += 32) {
        __syncthreads();
#pragma unroll
        for (int i = 0; i < 8; ++i) {
            const int f = i * 256 + t, col = f >> 3, kq = (f & 7) * 4;
            const float4 w = *(const float4*)&Bw[(n0 + col) * (long)K + k0 + kq];
            Bs[(kq + 0) * BSTR1 + col] = w.x;
            Bs[(kq + 1) * BSTR1 + col] = w.y;
            Bs[(kq + 2) * BSTR1 + col] = w.z;
            Bs[(kq + 3) * BSTR1 + col] = w.w;
        }
#pragma unroll
        for (int i = 0; i < 4; ++i) {
            const int f = i * 256 + t, row = f >> 3, kq = (f & 7) * 4;
            const float4 a = *(const float4*)&A[(m0 + row) * (long)K + k0 + kq];
            As[(kq + 0) * 132 + row] = a.x;
            As[(kq + 1) * 132 + row] = a.y;
            As[(kq + 2) * 132 + row] = a.z;
            As[(kq + 3) * 132 + row] = a.w;
        }
        __syncthreads();
#pragma unroll
        for (int kk = 0; kk < 32; ++kk) {
            const float4 a0 = *(const float4*)&As[kk * 132 + ty * 8];
            const float4 a1 = *(const float4*)&As[kk * 132 + ty * 8 + 4];
            float4 bb[4];
#pragma unroll
            for (int g = 0; g < 4; ++g)
                bb[g] = *(const float4*)&Bs[kk * BSTR1 + g * 64 + tx * 4];
            const float arr[8] = {a0.x, a0.y, a0.z, a0.w, a1.x, a1.y, a1.z, a1.w};
#pragma unroll
            for (int r = 0; r < 8; ++r)
#pragma unroll
                for (int g = 0; g < 4; ++g) {
                    acc[r][g][0] += arr[r] * bb[g].x;
                    acc[r][g][1] += arr[r] * bb[g].y;
                    acc[r][g][2] += arr[r] * bb[g].z;
                    acc[r][g][3] += arr[r] * bb[g].w;
                }
        }
    }

#pragma unroll
    for (int r = 0; r < 8; ++r) {
        const long row = m0 + ty * 8 + r;
#pragma unroll
        for (int g = 0; g < 4; ++g) {
            float v1 = -3.f, v2 = -3.f; int i1v = 0, bHi = 0;
#pragma unroll
            for (int d = 0; d < 4; ++d) {
                const long j = n0 + g * 64 + tx * 4 + d;
                const float pre = acc[r][g][d] + bias[j];
                const float c = fminf(fmaxf(pre, -1.f), 1.f);
                const int li = (tx & 3) * 4 + d;
                if (c > v1) { v2 = v1; v1 = c; i1v = li; }
                else if (c > v2) v2 = c;
                bHi |= (pre > 1.f - EPS1 && pre < 1.f + EPS1) ? 1 : 0;
            }
#pragma unroll
            for (int mk = 1; mk <= 2; mk <<= 1) {
                const float ov1 = __shfl_xor(v1, mk);
                const int   oi1 = __shfl_xor(i1v, mk);
                const float ov2 = __shfl_xor(v2, mk);
                bHi |= __shfl_xor(bHi, mk);
                if (ov1 > v1 || (ov1 == v1 && oi1 < i1v)) {
                    v2 = fmaxf(v1, ov2); v1 = ov1; i1v = oi1;
                } else v2 = fmaxf(v2, ov1);
            }
            if ((tx & 3) == 0) {
                const bool stable = (v1 >= 1.f) && (v2 >= 1.f) && !bHi;
                const int unc = ((v1 - v2 <= EPS1) && !stable) || (v1 <= -1.f + EPS1);
                const long blk = (n0 >> 4) + g * 4 + (tx >> 2);
                vOut[blk * MST + row] = v1;
                iOut[blk * MST + row] = (uint8_t)i1v;
                fOut[blk * MST + row] = (uint8_t)unc;
            }
        }
    }
}

// ---------------------------------------------------------------------------
// k1c: fp64 resolve of flagged L1 blocks (exact idx + value -> fp32 store).
__global__ __launch_bounds__(256)
void k1_resolve(const float* __restrict__ A, const float* __restrict__ Bw,
                const float* __restrict__ bias, const uint8_t* __restrict__ fIn,
                uint8_t* __restrict__ iFix, float* __restrict__ vFix)
{
    const int gtid = blockIdx.x * 256 + threadIdx.x;
    const int wid = gtid >> 6, lane = gtid & 63;
    const long per = (256L * MST) / ((gridDim.x * 256) >> 6);
    const long s0 = (long)wid * per;
    for (long c = 0; c < per; c += 64) {
        unsigned long long mask = __ballot(fIn[s0 + c + lane] != 0);
        while (mask) {
            const int bit = __builtin_ctzll(mask); mask &= mask - 1;
            const long s = s0 + c + bit;
            const int blk = (int)(s >> 13); const long row = s & (MST - 1);
            const float4* xp = (const float4*)&A[row * 1024 + lane * 16];
            const float4 x0 = xp[0], x1 = xp[1], x2 = xp[2], x3 = xp[3];
            double best = -3.0; int bi = 0;
            for (int u = 0; u < 16; ++u) {
                const float4* wp = (const float4*)&Bw[(long)(blk * 16 + u) * 1024 + lane * 16];
                const float4 w0 = wp[0], w1 = wp[1], w2 = wp[2], w3 = wp[3];
                double su = (double)x0.x * w0.x + (double)x0.y * w0.y
                          + (double)x0.z * w0.z + (double)x0.w * w0.w
                          + (double)x1.x * w1.x + (double)x1.y * w1.y
                          + (double)x1.z * w1.z + (double)x1.w * w1.w
                          + (double)x2.x * w2.x + (double)x2.y * w2.y
                          + (double)x2.z * w2.z + (double)x2.w * w2.w
                          + (double)x3.x * w3.x + (double)x3.y * w3.y
                          + (double)x3.z * w3.z + (double)x3.w * w3.w;
#pragma unroll
                for (int off = 32; off; off >>= 1) su += __shfl_xor(su, off);
                const double xu = fmin(fmax(su + (double)bias[blk * 16 + u], -1.0), 1.0);
                if (xu > best) { best = xu; bi = u; }
            }
            if (lane == 0) { iFix[s] = (uint8_t)bi; vFix[s] = (float)best; }
        }
    }
}

// ---------------------------------------------------------------------------
// Sparse GEMM v5: BK=16 (one LWTA block), N_blk=256, 8 waves x 8 rows
// (M_blk=64). acc[8][4]=32 VGPR -> ~60 total -> 8 waves/SIMD. Winner (v,kw)
// wave-uniform via readlane; gather = contiguous 1KB ds_read_b128.
// Double-buffered LDS (33 KB), single barrier per k-tile, reg-prefetch.
template<bool LWTA_OUT>
__global__ __launch_bounds__(512)
void sparse_gemm_v5(const float* __restrict__ vA, const uint8_t* __restrict__ iA,
                    const float* __restrict__ Bw, const float* __restrict__ bias,
                    int K, float eps,
                    float* __restrict__ vOut, uint8_t* __restrict__ iOut,
                    uint8_t* __restrict__ fOut, float* __restrict__ dOut, int N)
{
    __shared__ float Bs[2][16 * SB];
    const int t = threadIdx.x;
    const int lane = t & 63;
    const int w = t >> 6;                      // 0..7
    const long m0 = (long)blockIdx.y * 64;
    const long n0 = (long)blockIdx.x * 256;
    const long rbase = m0 + w * 8;
    const int nkt = K / 16;

    float acc[8][4];
#pragma unroll
    for (int r = 0; r < 8; ++r)
#pragma unroll
        for (int d = 0; d < 4; ++d) acc[r][d] = 0.f;

    // staging: 16 k x 256 cols = 1024 float4 slots / 512 thr = 2 per thread
    const float* bsrc[2]; int bdst[2];
#pragma unroll
    for (int i = 0; i < 2; ++i) {
        const int f = i * 512 + t, col = f >> 2, kq = (f & 3) * 4;
        bsrc[i] = &Bw[(n0 + col) * (long)K + kq];
        bdst[i] = kq * SB + col;
    }
    const long mrow = rbase + (lane & 7);   // lanes mirror the wave's 8 rows

    // prologue: tile 0
    float4 br[2];
#pragma unroll
    for (int i = 0; i < 2; ++i) br[i] = *(const float4*)(bsrc[i]);
    float    va = vA[mrow];
    unsigned ia = iA[mrow];
#pragma unroll
    for (int i = 0; i < 2; ++i) {
        Bs[0][bdst[i] + 0*SB] = br[i].x; Bs[0][bdst[i] + 1*SB] = br[i].y;
        Bs[0][bdst[i] + 2*SB] = br[i].z; Bs[0][bdst[i] + 3*SB] = br[i].w;
    }

    for (int kt = 0; kt < nkt; ++kt) {
        __syncthreads();
        const int cur = kt & 1;
        const bool more = kt + 1 < nkt;
        float nva = 0.f; unsigned nia = 0;
        if (more) {
            const int k0n = (kt + 1) * 16;
#pragma unroll
            for (int i = 0; i < 2; ++i) br[i] = *(const float4*)(bsrc[i] + k0n);
            nva = vA[(long)(kt + 1) * MST + mrow];
            nia = iA[(long)(kt + 1) * MST + mrow];
        }
        const float* bb = &Bs[cur][0];
#pragma unroll
        for (int r = 0; r < 8; ++r) {
            const float v = __uint_as_float(
                __builtin_amdgcn_readlane(__float_as_uint(va), r));
            const int kw = __builtin_amdgcn_readlane((int)ia, r);
            const float4 b = *(const float4*)&bb[kw * SB + lane * 4];
            acc[r][0] += v * b.x; acc[r][1] += v * b.y;
            acc[r][2] += v * b.z; acc[r][3] += v * b.w;
        }
        if (more) {
            const int nxt = cur ^ 1;
#pragma unroll
            for (int i = 0; i < 2; ++i) {
                Bs[nxt][bdst[i] + 0*SB] = br[i].x; Bs[nxt][bdst[i] + 1*SB] = br[i].y;
                Bs[nxt][bdst[i] + 2*SB] = br[i].z; Bs[nxt][bdst[i] + 3*SB] = br[i].w;
            }
            va = nva; ia = nia;
        }
    }

    const float4 bv4 = *(const float4*)&bias[n0 + lane * 4];
    const float bias4[4] = {bv4.x, bv4.y, bv4.z, bv4.w};

    if (LWTA_OUT) {
#pragma unroll
        for (int r = 0; r < 8; ++r) {
            const long row = rbase + r;
            float v1 = -3.f, v2 = -3.f; int i1v = 0, bHi = 0;
#pragma unroll
            for (int d = 0; d < 4; ++d) {
                const float pre = acc[r][d] + bias4[d];
                const float cv = fminf(fmaxf(pre, -1.f), 1.f);
                const int li = (lane & 3) * 4 + d;
                if (cv > v1) { v2 = v1; v1 = cv; i1v = li; }
                else if (cv > v2) v2 = cv;
                bHi |= (pre > 1.f - eps && pre < 1.f + eps) ? 1 : 0;
            }
#pragma unroll
            for (int mk = 1; mk <= 2; mk <<= 1) {
                const float ov1 = __shfl_xor(v1, mk);
                const int   oi1 = __shfl_xor(i1v, mk);
                const float ov2 = __shfl_xor(v2, mk);
                bHi |= __shfl_xor(bHi, mk);
                if (ov1 > v1 || (ov1 == v1 && oi1 < i1v)) {
                    v2 = fmaxf(v1, ov2); v1 = ov1; i1v = oi1;
                } else v2 = fmaxf(v2, ov1);
            }
            if ((lane & 3) == 0) {
                const bool stable = (v1 >= 1.f) && (v2 >= 1.f) && !bHi;
                const int unc = ((v1 - v2 <= eps) && !stable) || (v1 <= -1.f + eps);
                const long blk = (n0 >> 4) + (lane >> 2);
                vOut[blk * MST + row] = v1;
                iOut[blk * MST + row] = (uint8_t)i1v;
                fOut[blk * MST + row] = (uint8_t)unc;
            }
        }
    } else {
#pragma unroll
        for (int r = 0; r < 8; ++r) {
            const long row = rbase + r;
            float4 o;
            o.x = acc[r][0] + bias4[0];
            o.y = acc[r][1] + bias4[1];
            o.z = acc[r][2] + bias4[2];
            o.w = acc[r][3] + bias4[3];
            *(float4*)&dOut[row * (long)N + n0 + lane * 4] = o;
        }
    }
}

// ---------------------------------------------------------------------------
// k2b v2: fp64 resolve of flagged L2 blocks; recomputes the row's 256 h1
// winner values in fp64 from x.W1 (wave-cooperative dots, x row in regs).
__global__ __launch_bounds__(256)
void k2_resolve(const float* __restrict__ x, const float* __restrict__ W1,
                const float* __restrict__ b1, const uint8_t* __restrict__ iA,
                const float* __restrict__ W2r, const float* __restrict__ b2,
                const uint8_t* __restrict__ fIn, uint8_t* __restrict__ iFix,
                float* __restrict__ vFix)
{
    const int gtid = blockIdx.x * 256 + threadIdx.x;
    const int wid = gtid >> 6, lane = gtid & 63;
    const long per = (256L * MST) / ((gridDim.x * 256) >> 6);
    const long s0 = (long)wid * per;
    for (long c = 0; c < per; c += 64) {
        unsigned long long mask = __ballot(fIn[s0 + c + lane] != 0);
        while (mask) {
            const int bit = __builtin_ctzll(mask); mask &= mask - 1;
            const long s = s0 + c + bit;
            const int gblk = (int)(s >> 13); const long row = s & (MST - 1);

            // x row into regs: 16 floats/lane
            const float4* xp = (const float4*)&x[row * 1024 + lane * 16];
            const float4 x0 = xp[0], x1 = xp[1], x2 = xp[2], x3 = xp[3];

            // recompute fp64 h1 winner values for all 256 kblocks
            double hv[4]; int kp[4];
            for (int kq = 0; kq < 64; ++kq) {
#pragma unroll
                for (int j = 0; j < 4; ++j) {
                    const int kb = kq * 4 + j;
                    const int col = kb * 16 + (int)iA[(long)kb * MST + row];
                    const float4* wp = (const float4*)&W1[(long)col * 1024 + lane * 16];
                    const float4 w0 = wp[0], w1 = wp[1], w2 = wp[2], w3 = wp[3];
                    double p = (double)x0.x * w0.x + (double)x0.y * w0.y
                             + (double)x0.z * w0.z + (double)x0.w * w0.w
                             + (double)x1.x * w1.x + (double)x1.y * w1.y
                             + (double)x1.z * w1.z + (double)x1.w * w1.w
                             + (double)x2.x * w2.x + (double)x2.y * w2.y
                             + (double)x2.z * w2.z + (double)x2.w * w2.w
                             + (double)x3.x * w3.x + (double)x3.y * w3.y
                             + (double)x3.z * w3.z + (double)x3.w * w3.w;
#pragma unroll
                    for (int off = 32; off; off >>= 1) p += __shfl_xor(p, off);
                    if (lane == kq) {
                        hv[j] = fmin(fmax(p + (double)b1[col], -1.0), 1.0);
                        kp[j] = col;
                    }
                }
            }

            // 16-unit fp64 argmax over the sparse h1
            double best = -3.0; int bi = 0;
            for (int u = 0; u < 16; ++u) {
                const float* wr = &W2r[(long)(gblk * 16 + u) * 4096];
                double su = hv[0] * (double)wr[kp[0]] + hv[1] * (double)wr[kp[1]]
                          + hv[2] * (double)wr[kp[2]] + hv[3] * (double)wr[kp[3]];
#pragma unroll
                for (int off = 32; off; off >>= 1) su += __shfl_xor(su, off);
                const double xu = fmin(fmax(su + (double)b2[gblk * 16 + u], -1.0), 1.0);
                if (xu > best) { best = xu; bi = u; }
            }
            if (lane == 0) { iFix[s] = (uint8_t)bi; vFix[s] = (float)best; }
        }
    }
}

// ---------------------------------------------------------------------------
extern "C" void kernel_launch(void* const* d_in, const int* in_sizes, int n_in,
                              void* d_out, int out_size, void* d_ws, size_t ws_size,
                              hipStream_t stream)
{
    const float* x    = (const float*)d_in[0];
    const float* W1   = (const float*)d_in[1];
    const float* b1   = (const float*)d_in[2];
    const float* W2   = (const float*)d_in[3];
    const float* b2   = (const float*)d_in[4];
    const float* Wout = (const float*)d_in[5];
    const float* bout = (const float*)d_in[6];
    float* out = (float*)d_out;
    (void)in_sizes; (void)n_in; (void)out_size; (void)ws_size;

    const int B = 8192, Din = 1024, H = 4096, Dout = 1024;

    char* ws = (char*)d_ws;
    float*   v1f = (float*)ws;                        //  8 MB [256][8192]
    uint8_t* i1  = (uint8_t*)(ws + ( 8ll << 20));     //  2 MB
    uint8_t* f1  = (uint8_t*)(ws + (10ll << 20));     //  2 MB
    float*   v2f = (float*)(ws + (12ll << 20));       //  8 MB
    uint8_t* i2  = (uint8_t*)(ws + (20ll << 20));     //  2 MB
    uint8_t* f2  = (uint8_t*)(ws + (22ll << 20));     //  2 MB

    dim3 blk(256);
    k1a_dense_f32_flags<<<dim3(H / 256, B / 128), blk, 0, stream>>>(
        x, W1, b1, Din, v1f, i1, f1);
    k1_resolve<<<4096, blk, 0, stream>>>(x, W1, b1, f1, i1, v1f);
    sparse_gemm_v5<true><<<dim3(H / 256, B / 64), dim3(512), 0, stream>>>(
        v1f, i1, W2, b2, H, EPS2, v2f, i2, f2, nullptr, H);
    k2_resolve<<<4096, blk, 0, stream>>>(x, W1, b1, i1, W2, b2, f2, i2, v2f);
    sparse_gemm_v5<false><<<dim3(Dout / 256, B / 64), dim3(512), 0, stream>>>(
        v2f, i2, Wout, bout, H, 0.f, nullptr, nullptr, nullptr, out, Dout);
}

// Round 10
// 1832.930 us; speedup vs baseline: 1.6399x; 1.6399x over previous
//
#include <hip/hip_runtime.h>
#include <stdint.h>

// LWTA MLP, decision/value-split.
//   k1a: dense split-bf16 MFMA GEMM -> winner idx + fp32 value + flags
//        (3-product hi/lo split: err ~5e-6 rms << EPS1=3e-4 flag margin)
//   k1c: fp64 exact resolve of flagged L1 blocks
//   k2a: sparse fp32 GEMM v5 (8 rows/wave, conflict-free gather)
//   k2b: fp64 resolve of flagged L2 blocks (recomputes h1 fp64 on the fly)
//   k3 : sparse fp32 GEMM v5 -> dense out
// EPS2 tightened to 3e-5 (decision err budget ~5e-6 worst) to cut k2b flags.
// Metadata TRANSPOSED [kblock][8192]. No __launch_bounds__ min-waves.

#define EPS1 3.0e-4f
#define EPS2 3.0e-5f
#define MST  8192L   // metadata row stride (batch size)
#define SB   260     // sparse-GEMM LDS row stride (words)

typedef __attribute__((ext_vector_type(8))) short bf16x8;
typedef __attribute__((ext_vector_type(4))) float f32x4;

// ---------------------------------------------------------------------------
// k1a: dense MFMA GEMM (split-bf16), 128j x 128m tile, BK=32, 256 thr.
// D = A(W1 16x32) . B(x^T 32x16): D col = batch m (lane&15),
// D row = unit j ((lane>>4)*4+reg) -> one D-tile = one LWTA block x 16 batch.
__global__ __launch_bounds__(256)
void k1a_mfma_flags(const float* __restrict__ x, const float* __restrict__ W1,
                    const float* __restrict__ bias, int K,
                    float* __restrict__ vOut,
                    uint8_t* __restrict__ iOut, uint8_t* __restrict__ fOut)
{
    // rows = exactly one 32-k tile (64B): b128 frag reads hit all 32 banks evenly
    __shared__ __align__(16) short A_hi[128 * 32];
    __shared__ __align__(16) short A_lo[128 * 32];
    __shared__ __align__(16) short B_hi[128 * 32];
    __shared__ __align__(16) short B_lo[128 * 32];

    const int t = threadIdx.x;
    const int lane = t & 63;
    const int w = t >> 6;                       // wave 0..3
    const int g = lane >> 4, ml = lane & 15;
    const long n0j = (long)blockIdx.x * 128;    // unit offset
    const long m0  = (long)blockIdx.y * 128;    // batch offset

    f32x4 acc[2][8];
#pragma unroll
    for (int jf = 0; jf < 2; ++jf)
#pragma unroll
        for (int mf = 0; mf < 8; ++mf) acc[jf][mf] = (f32x4){0.f, 0.f, 0.f, 0.f};

    for (int k0 = 0; k0 < K; k0 += 32) {
        __syncthreads();
        // stage + split: 1024 float4 slots each for W1 and x; 4 per thread
#pragma unroll
        for (int i = 0; i < 4; ++i) {
            const int s = i * 256 + t, row = s >> 3, kq = (s & 7) * 4;
            const float4 fa = *(const float4*)&W1[(n0j + row) * (long)K + k0 + kq];
            const float4 fb = *(const float4*)&x[(m0 + row) * (long)K + k0 + kq];
            const float fav[4] = {fa.x, fa.y, fa.z, fa.w};
            const float fbv[4] = {fb.x, fb.y, fb.z, fb.w};
            short4 ah, al, bh, bl;
            short* ahp = (short*)&ah; short* alp = (short*)&al;
            short* bhp = (short*)&bh; short* blp = (short*)&bl;
#pragma unroll
            for (int e = 0; e < 4; ++e) {
                unsigned ua = __float_as_uint(fav[e]) & 0xFFFF0000u;
                float ra = fav[e] - __uint_as_float(ua);
                unsigned la = __float_as_uint(ra) & 0xFFFF0000u;
                ahp[e] = (short)(ua >> 16); alp[e] = (short)(la >> 16);
                unsigned ub = __float_as_uint(fbv[e]) & 0xFFFF0000u;
                float rb = fbv[e] - __uint_as_float(ub);
                unsigned lb = __float_as_uint(rb) & 0xFFFF0000u;
                bhp[e] = (short)(ub >> 16); blp[e] = (short)(lb >> 16);
            }
            *(short4*)&A_hi[row * 32 + kq] = ah;
            *(short4*)&A_lo[row * 32 + kq] = al;
            *(short4*)&B_hi[row * 32 + kq] = bh;
            *(short4*)&B_lo[row * 32 + kq] = bl;
        }
        __syncthreads();

        // A frags: lane reads unit row (lane&15), k-slice (lane>>4)*8
        bf16x8 ahi[2], alo[2];
#pragma unroll
        for (int jf = 0; jf < 2; ++jf) {
            const int jr = w * 32 + jf * 16 + ml;
            ahi[jf] = *(const bf16x8*)&A_hi[jr * 32 + g * 8];
            alo[jf] = *(const bf16x8*)&A_lo[jr * 32 + g * 8];
        }
#pragma unroll
        for (int mf = 0; mf < 8; ++mf) {
            const int mr = mf * 16 + ml;
            const bf16x8 bhi = *(const bf16x8*)&B_hi[mr * 32 + g * 8];
            const bf16x8 blo = *(const bf16x8*)&B_lo[mr * 32 + g * 8];
#pragma unroll
            for (int jf = 0; jf < 2; ++jf) {
                acc[jf][mf] = __builtin_amdgcn_mfma_f32_16x16x32_bf16(
                    ahi[jf], bhi, acc[jf][mf], 0, 0, 0);
                acc[jf][mf] = __builtin_amdgcn_mfma_f32_16x16x32_bf16(
                    ahi[jf], blo, acc[jf][mf], 0, 0, 0);
                acc[jf][mf] = __builtin_amdgcn_mfma_f32_16x16x32_bf16(
                    alo[jf], bhi, acc[jf][mf], 0, 0, 0);
            }
        }
    }

    // epilogue: each (jf,mf) D-tile = one LWTA 16-block x 16 batch
#pragma unroll
    for (int jf = 0; jf < 2; ++jf) {
        const long jb = n0j + w * 32 + jf * 16;
        const float4 bs4 = *(const float4*)&bias[jb + g * 4];
        const float bsv[4] = {bs4.x, bs4.y, bs4.z, bs4.w};
        const long gblk = jb >> 4;
#pragma unroll
        for (int mf = 0; mf < 8; ++mf) {
            float v1 = -3.f, v2 = -3.f; int i1v = 0, bHi = 0;
#pragma unroll
            for (int reg = 0; reg < 4; ++reg) {
                const float pre = acc[jf][mf][reg] + bsv[reg];
                const float cv = fminf(fmaxf(pre, -1.f), 1.f);
                const int li = g * 4 + reg;
                if (cv > v1) { v2 = v1; v1 = cv; i1v = li; }
                else if (cv > v2) v2 = cv;
                bHi |= (pre > 1.f - EPS1 && pre < 1.f + EPS1) ? 1 : 0;
            }
#pragma unroll
            for (int mk = 16; mk <= 32; mk <<= 1) {
                const float ov1 = __shfl_xor(v1, mk);
                const int   oi1 = __shfl_xor(i1v, mk);
                const float ov2 = __shfl_xor(v2, mk);
                bHi |= __shfl_xor(bHi, mk);
                if (ov1 > v1 || (ov1 == v1 && oi1 < i1v)) {
                    v2 = fmaxf(v1, ov2); v1 = ov1; i1v = oi1;
                } else v2 = fmaxf(v2, ov1);
            }
            if (g == 0) {
                const bool stable = (v1 >= 1.f) && (v2 >= 1.f) && !bHi;
                const int unc = ((v1 - v2 <= EPS1) && !stable) || (v1 <= -1.f + EPS1);
                const long row = m0 + mf * 16 + ml;
                vOut[gblk * MST + row] = v1;
                iOut[gblk * MST + row] = (uint8_t)i1v;
                fOut[gblk * MST + row] = (uint8_t)unc;
            }
        }
    }
}

// ---------------------------------------------------------------------------
// k1c: fp64 resolve of flagged L1 blocks (exact idx + value -> fp32 store).
__global__ __launch_bounds__(256)
void k1_resolve(const float* __restrict__ A, const float* __restrict__ Bw,
                const float* __restrict__ bias, const uint8_t* __restrict__ fIn,
                uint8_t* __restrict__ iFix, float* __restrict__ vFix)
{
    const int gtid = blockIdx.x * 256 + threadIdx.x;
    const int wid = gtid >> 6, lane = gtid & 63;
    const long per = (256L * MST) / ((gridDim.x * 256) >> 6);
    const long s0 = (long)wid * per;
    for (long c = 0; c < per; c += 64) {
        unsigned long long mask = __ballot(fIn[s0 + c + lane] != 0);
        while (mask) {
            const int bit = __builtin_ctzll(mask); mask &= mask - 1;
            const long s = s0 + c + bit;
            const int blk = (int)(s >> 13); const long row = s & (MST - 1);
            const float4* xp = (const float4*)&A[row * 1024 + lane * 16];
            const float4 x0 = xp[0], x1 = xp[1], x2 = xp[2], x3 = xp[3];
            double best = -3.0; int bi = 0;
            for (int u = 0; u < 16; ++u) {
                const float4* wp = (const float4*)&Bw[(long)(blk * 16 + u) * 1024 + lane * 16];
                const float4 w0 = wp[0], w1 = wp[1], w2 = wp[2], w3 = wp[3];
                double su = (double)x0.x * w0.x + (double)x0.y * w0.y
                          + (double)x0.z * w0.z + (double)x0.w * w0.w
                          + (double)x1.x * w1.x + (double)x1.y * w1.y
                          + (double)x1.z * w1.z + (double)x1.w * w1.w
                          + (double)x2.x * w2.x + (double)x2.y * w2.y
                          + (double)x2.z * w2.z + (double)x2.w * w2.w
                          + (double)x3.x * w3.x + (double)x3.y * w3.y
                          + (double)x3.z * w3.z + (double)x3.w * w3.w;
#pragma unroll
                for (int off = 32; off; off >>= 1) su += __shfl_xor(su, off);
                const double xu = fmin(fmax(su + (double)bias[blk * 16 + u], -1.0), 1.0);
                if (xu > best) { best = xu; bi = u; }
            }
            if (lane == 0) { iFix[s] = (uint8_t)bi; vFix[s] = (float)best; }
        }
    }
}

// ---------------------------------------------------------------------------
// Sparse GEMM v5: BK=16 (one LWTA block), N_blk=256, 8 waves x 8 rows
// (M_blk=64). acc[8][4]=32 VGPR -> ~48 total -> high occupancy. Winner (v,kw)
// wave-uniform via readlane; gather = contiguous 1KB ds_read_b128.
// Double-buffered LDS (33 KB), single barrier per k-tile, reg-prefetch.
template<bool LWTA_OUT>
__global__ __launch_bounds__(512)
void sparse_gemm_v5(const float* __restrict__ vA, const uint8_t* __restrict__ iA,
                    const float* __restrict__ Bw, const float* __restrict__ bias,
                    int K, float eps,
                    float* __restrict__ vOut, uint8_t* __restrict__ iOut,
                    uint8_t* __restrict__ fOut, float* __restrict__ dOut, int N)
{
    __shared__ float Bs[2][16 * SB];
    const int t = threadIdx.x;
    const int lane = t & 63;
    const int w = t >> 6;                      // 0..7
    const long m0 = (long)blockIdx.y * 64;
    const long n0 = (long)blockIdx.x * 256;
    const long rbase = m0 + w * 8;
    const int nkt = K / 16;

    float acc[8][4];
#pragma unroll
    for (int r = 0; r < 8; ++r)
#pragma unroll
        for (int d = 0; d < 4; ++d) acc[r][d] = 0.f;

    const float* bsrc[2]; int bdst[2];
#pragma unroll
    for (int i = 0; i < 2; ++i) {
        const int f = i * 512 + t, col = f >> 2, kq = (f & 3) * 4;
        bsrc[i] = &Bw[(n0 + col) * (long)K + kq];
        bdst[i] = kq * SB + col;
    }
    const long mrow = rbase + (lane & 7);

    float4 br[2];
#pragma unroll
    for (int i = 0; i < 2; ++i) br[i] = *(const float4*)(bsrc[i]);
    float    va = vA[mrow];
    unsigned ia = iA[mrow];
#pragma unroll
    for (int i = 0; i < 2; ++i) {
        Bs[0][bdst[i] + 0*SB] = br[i].x; Bs[0][bdst[i] + 1*SB] = br[i].y;
        Bs[0][bdst[i] + 2*SB] = br[i].z; Bs[0][bdst[i] + 3*SB] = br[i].w;
    }

    for (int kt = 0; kt < nkt; ++kt) {
        __syncthreads();
        const int cur = kt & 1;
        const bool more = kt + 1 < nkt;
        float nva = 0.f; unsigned nia = 0;
        if (more) {
            const int k0n = (kt + 1) * 16;
#pragma unroll
            for (int i = 0; i < 2; ++i) br[i] = *(const float4*)(bsrc[i] + k0n);
            nva = vA[(long)(kt + 1) * MST + mrow];
            nia = iA[(long)(kt + 1) * MST + mrow];
        }
        const float* bb = &Bs[cur][0];
#pragma unroll
        for (int r = 0; r < 8; ++r) {
            const float v = __uint_as_float(
                __builtin_amdgcn_readlane(__float_as_uint(va), r));
            const int kw = __builtin_amdgcn_readlane((int)ia, r);
            const float4 b = *(const float4*)&bb[kw * SB + lane * 4];
            acc[r][0] += v * b.x; acc[r][1] += v * b.y;
            acc[r][2] += v * b.z; acc[r][3] += v * b.w;
        }
        if (more) {
            const int nxt = cur ^ 1;
#pragma unroll
            for (int i = 0; i < 2; ++i) {
                Bs[nxt][bdst[i] + 0*SB] = br[i].x; Bs[nxt][bdst[i] + 1*SB] = br[i].y;
                Bs[nxt][bdst[i] + 2*SB] = br[i].z; Bs[nxt][bdst[i] + 3*SB] = br[i].w;
            }
            va = nva; ia = nia;
        }
    }

    const float4 bv4 = *(const float4*)&bias[n0 + lane * 4];
    const float bias4[4] = {bv4.x, bv4.y, bv4.z, bv4.w};

    if (LWTA_OUT) {
#pragma unroll
        for (int r = 0; r < 8; ++r) {
            const long row = rbase + r;
            float v1 = -3.f, v2 = -3.f; int i1v = 0, bHi = 0;
#pragma unroll
            for (int d = 0; d < 4; ++d) {
                const float pre = acc[r][d] + bias4[d];
                const float cv = fminf(fmaxf(pre, -1.f), 1.f);
                const int li = (lane & 3) * 4 + d;
                if (cv > v1) { v2 = v1; v1 = cv; i1v = li; }
                else if (cv > v2) v2 = cv;
                bHi |= (pre > 1.f - eps && pre < 1.f + eps) ? 1 : 0;
            }
#pragma unroll
            for (int mk = 1; mk <= 2; mk <<= 1) {
                const float ov1 = __shfl_xor(v1, mk);
                const int   oi1 = __shfl_xor(i1v, mk);
                const float ov2 = __shfl_xor(v2, mk);
                bHi |= __shfl_xor(bHi, mk);
                if (ov1 > v1 || (ov1 == v1 && oi1 < i1v)) {
                    v2 = fmaxf(v1, ov2); v1 = ov1; i1v = oi1;
                } else v2 = fmaxf(v2, ov1);
            }
            if ((lane & 3) == 0) {
                const bool stable = (v1 >= 1.f) && (v2 >= 1.f) && !bHi;
                const int unc = ((v1 - v2 <= eps) && !stable) || (v1 <= -1.f + eps);
                const long blk = (n0 >> 4) + (lane >> 2);
                vOut[blk * MST + row] = v1;
                iOut[blk * MST + row] = (uint8_t)i1v;
                fOut[blk * MST + row] = (uint8_t)unc;
            }
        }
    } else {
#pragma unroll
        for (int r = 0; r < 8; ++r) {
            const long row = rbase + r;
            float4 o;
            o.x = acc[r][0] + bias4[0];
            o.y = acc[r][1] + bias4[1];
            o.z = acc[r][2] + bias4[2];
            o.w = acc[r][3] + bias4[3];
            *(float4*)&dOut[row * (long)N + n0 + lane * 4] = o;
        }
    }
}

// ---------------------------------------------------------------------------
// k2b: fp64 resolve of flagged L2 blocks; recomputes the row's 256 h1
// winner values in fp64 from x.W1 (wave-cooperative dots).
__global__ __launch_bounds__(256)
void k2_resolve(const float* __restrict__ x, const float* __restrict__ W1,
                const float* __restrict__ b1, const uint8_t* __restrict__ iA,
                const float* __restrict__ W2r, const float* __restrict__ b2,
                const uint8_t* __restrict__ fIn, uint8_t* __restrict__ iFix,
                float* __restrict__ vFix)
{
    const int gtid = blockIdx.x * 256 + threadIdx.x;
    const int wid = gtid >> 6, lane = gtid & 63;
    const long per = (256L * MST) / ((gridDim.x * 256) >> 6);
    const long s0 = (long)wid * per;
    for (long c = 0; c < per; c += 64) {
        unsigned long long mask = __ballot(fIn[s0 + c + lane] != 0);
        while (mask) {
            const int bit = __builtin_ctzll(mask); mask &= mask - 1;
            const long s = s0 + c + bit;
            const int gblk = (int)(s >> 13); const long row = s & (MST - 1);

            const float4* xp = (const float4*)&x[row * 1024 + lane * 16];
            const float4 x0 = xp[0], x1 = xp[1], x2 = xp[2], x3 = xp[3];

            double hv[4]; int kp[4];
            for (int kq = 0; kq < 64; ++kq) {
#pragma unroll
                for (int j = 0; j < 4; ++j) {
                    const int kb = kq * 4 + j;
                    const int col = kb * 16 + (int)iA[(long)kb * MST + row];
                    const float4* wp = (const float4*)&W1[(long)col * 1024 + lane * 16];
                    const float4 w0 = wp[0], w1 = wp[1], w2 = wp[2], w3 = wp[3];
                    double p = (double)x0.x * w0.x + (double)x0.y * w0.y
                             + (double)x0.z * w0.z + (double)x0.w * w0.w
                             + (double)x1.x * w1.x + (double)x1.y * w1.y
                             + (double)x1.z * w1.z + (double)x1.w * w1.w
                             + (double)x2.x * w2.x + (double)x2.y * w2.y
                             + (double)x2.z * w2.z + (double)x2.w * w2.w
                             + (double)x3.x * w3.x + (double)x3.y * w3.y
                             + (double)x3.z * w3.z + (double)x3.w * w3.w;
#pragma unroll
                    for (int off = 32; off; off >>= 1) p += __shfl_xor(p, off);
                    if (lane == kq) {
                        hv[j] = fmin(fmax(p + (double)b1[col], -1.0), 1.0);
                        kp[j] = col;
                    }
                }
            }

            double best = -3.0; int bi = 0;
            for (int u = 0; u < 16; ++u) {
                const float* wr = &W2r[(long)(gblk * 16 + u) * 4096];
                double su = hv[0] * (double)wr[kp[0]] + hv[1] * (double)wr[kp[1]]
                          + hv[2] * (double)wr[kp[2]] + hv[3] * (double)wr[kp[3]];
#pragma unroll
                for (int off = 32; off; off >>= 1) su += __shfl_xor(su, off);
                const double xu = fmin(fmax(su + (double)b2[gblk * 16 + u], -1.0), 1.0);
                if (xu > best) { best = xu; bi = u; }
            }
            if (lane == 0) { iFix[s] = (uint8_t)bi; vFix[s] = (float)best; }
        }
    }
}

// ---------------------------------------------------------------------------
extern "C" void kernel_launch(void* const* d_in, const int* in_sizes, int n_in,
                              void* d_out, int out_size, void* d_ws, size_t ws_size,
                              hipStream_t stream)
{
    const float* x    = (const float*)d_in[0];
    const float* W1   = (const float*)d_in[1];
    const float* b1   = (const float*)d_in[2];
    const float* W2   = (const float*)d_in[3];
    const float* b2   = (const float*)d_in[4];
    const float* Wout = (const float*)d_in[5];
    const float* bout = (const float*)d_in[6];
    float* out = (float*)d_out;
    (void)in_sizes; (void)n_in; (void)out_size; (void)ws_size;

    const int B = 8192, Din = 1024, H = 4096, Dout = 1024;

    char* ws = (char*)d_ws;
    float*   v1f = (float*)ws;                        //  8 MB [256][8192]
    uint8_t* i1  = (uint8_t*)(ws + ( 8ll << 20));     //  2 MB
    uint8_t* f1  = (uint8_t*)(ws + (10ll << 20));     //  2 MB
    float*   v2f = (float*)(ws + (12ll << 20));       //  8 MB
    uint8_t* i2  = (uint8_t*)(ws + (20ll << 20));     //  2 MB
    uint8_t* f2  = (uint8_t*)(ws + (22ll << 20));     //  2 MB

    dim3 blk(256);
    // k1a: grid (units/128, batch/128)
    k1a_mfma_flags<<<dim3(H / 128, B / 128), blk, 0, stream>>>(
        x, W1, b1, Din, v1f, i1, f1);
    k1_resolve<<<4096, blk, 0, stream>>>(x, W1, b1, f1, i1, v1f);
    sparse_gemm_v5<true><<<dim3(H / 256, B / 64), dim3(512), 0, stream>>>(
        v1f, i1, W2, b2, H, EPS2, v2f, i2, f2, nullptr, H);
    k2_resolve<<<4096, blk, 0, stream>>>(x, W1, b1, i1, W2, b2, f2, i2, v2f);
    sparse_gemm_v5<false><<<dim3(Dout / 256, B / 64), dim3(512), 0, stream>>>(
        v2f, i2, Wout, bout, H, 0.f, nullptr, nullptr, nullptr, out, Dout);
}